// Round 8
// baseline (377.302 us; speedup 1.0000x reference)
//
#include <hip/hip_runtime.h>
#include <math.h>

#define BB 64
#define NN 8192
#define LL 64
#define KK 20
#define TILE 128
#define NT 8        // tiles per block
#define CHUNKS 8    // blocks per batch entry: CHUNKS*NT*TILE == NN
#define ZSB 72      // zhl/mhl row stride (ushorts): 144 B
#define ZTS 140     // zT row stride (ushorts): 280 B
#define PTTS 136    // ptT row stride (ushorts): 272 B, 16B-aligned b128 reads
#define AS 132      // aug row stride (floats)
#define TS 68       // iaT row stride

typedef float f32x4 __attribute__((ext_vector_type(4)));
typedef short s16x8 __attribute__((ext_vector_type(8)));
typedef short s16x4 __attribute__((ext_vector_type(4)));
typedef unsigned short u16x4 __attribute__((ext_vector_type(4)));
typedef unsigned short u16x2 __attribute__((ext_vector_type(2)));

#define MFMA_BF16 __builtin_amdgcn_mfma_f32_16x16x32_bf16

__device__ __forceinline__ unsigned short f2bf(float f) {   // RNE fp32->bf16
    unsigned int u = __float_as_uint(f);
    u += 0x7fffu + ((u >> 16) & 1u);
    return (unsigned short)(u >> 16);
}
__device__ __forceinline__ float bf2f(unsigned short h) {
    return __uint_as_float(((unsigned int)h) << 16);
}

// ---------------------------------------------------------------------------
// ws layout (floats): IA @0, M @4096, bias @8192, nk @9472, macc @10752,
// cnt(int) @92672. Requires ws_size >= 370,944 B.
// ---------------------------------------------------------------------------

// IA = I - A ; M = inv(I + IA @ IA^T), Gauss-Jordan (SPD, no pivoting).
// Pipelined 1-barrier-per-pivot: row r's 4 col-quarter threads live in ONE
// wave (r = t>>2, g = t&3), so row k+1 can normalize itself into the next
// prow buffer wave-synchronously inside pivot k's update phase.
__global__ __launch_bounds__(256) void k_setup(const float* __restrict__ A,
                                               float* __restrict__ IA,
                                               float* __restrict__ M) {
    __shared__ __align__(16) float iaT[64][TS];
    __shared__ __align__(16) float aug[64][AS];
    __shared__ __align__(16) float prowbuf[2][AS];
    int t = threadIdx.x;
    for (int i = t; i < 4096; i += 256) {
        int r = i >> 6, c = i & 63;
        float v = (r == c ? 1.0f : 0.0f) - A[i];
        IA[i] = v;
        iaT[c][r] = v;
    }
    __syncthreads();
    {   // S = I + IA·IAᵀ, 4x4 blocks per thread
        int r0 = (t >> 4) << 2;
        int c0 = (t & 15) << 2;
        float s[4][4];
        #pragma unroll
        for (int a = 0; a < 4; ++a)
            #pragma unroll
            for (int bq = 0; bq < 4; ++bq) s[a][bq] = 0.f;
        for (int l = 0; l < 64; ++l) {
            float4 u = *(const float4*)&iaT[l][r0];
            float4 v = *(const float4*)&iaT[l][c0];
            float uu[4] = {u.x, u.y, u.z, u.w};
            float vv[4] = {v.x, v.y, v.z, v.w};
            #pragma unroll
            for (int a = 0; a < 4; ++a)
                #pragma unroll
                for (int bq = 0; bq < 4; ++bq) s[a][bq] += uu[a] * vv[bq];
        }
        #pragma unroll
        for (int a = 0; a < 4; ++a) {
            int r = r0 + a;
            float4 w;
            w.x = s[a][0] + (r == c0 + 0 ? 1.f : 0.f);
            w.y = s[a][1] + (r == c0 + 1 ? 1.f : 0.f);
            w.z = s[a][2] + (r == c0 + 2 ? 1.f : 0.f);
            w.w = s[a][3] + (r == c0 + 3 ? 1.f : 0.f);
            *(float4*)&aug[r][c0] = w;
            float4 id;
            id.x = (r == c0 + 0 ? 1.f : 0.f);
            id.y = (r == c0 + 1 ? 1.f : 0.f);
            id.z = (r == c0 + 2 ? 1.f : 0.f);
            id.w = (r == c0 + 3 ? 1.f : 0.f);
            *(float4*)&aug[r][64 + c0] = id;
        }
    }
    __syncthreads();
    int r = t >> 2;             // row; 4 quarter-threads of a row share a wave
    int cbase = (t & 3) * 32;   // 32-col block
    if (r == 0) {               // prologue: normalize row 0 into prowbuf[0]
        float pivinv = 1.0f / aug[0][0];
        #pragma unroll
        for (int i = 0; i < 8; ++i) {
            float4 v = *(const float4*)&aug[0][cbase + 4 * i];
            v.x *= pivinv; v.y *= pivinv; v.z *= pivinv; v.w *= pivinv;
            *(float4*)&prowbuf[0][cbase + 4 * i] = v;
        }
    }
    __syncthreads();
    for (int k = 0; k < 64; ++k) {
        const float* prow = prowbuf[k & 1];
        float* prown = prowbuf[(k + 1) & 1];
        if (r == k) {
            // finalize pivot row: copy normalized prow into aug
            #pragma unroll
            for (int i = 0; i < 8; ++i)
                *(float4*)&aug[r][cbase + 4 * i] = *(const float4*)&prow[cbase + 4 * i];
        } else {
            float f = aug[r][k];
            float4 v[8];
            #pragma unroll
            for (int i = 0; i < 8; ++i) {
                float4 p = *(const float4*)&prow[cbase + 4 * i];
                float4 a = *(const float4*)&aug[r][cbase + 4 * i];
                a.x -= f * p.x; a.y -= f * p.y; a.z -= f * p.z; a.w -= f * p.w;
                *(float4*)&aug[r][cbase + 4 * i] = a;
                v[i] = a;
            }
            if (r == k + 1) {
                // wave-synchronous: sibling lane just wrote the updated pivot
                float pivinv = 1.0f / aug[k + 1][k + 1];
                #pragma unroll
                for (int i = 0; i < 8; ++i) {
                    float4 w = v[i];
                    w.x *= pivinv; w.y *= pivinv; w.z *= pivinv; w.w *= pivinv;
                    *(float4*)&prown[cbase + 4 * i] = w;
                }
            }
        }
        __syncthreads();
    }
    for (int i = t; i < 4096; i += 256) {
        int rr = i >> 6, c = i & 63;
        M[i] = aug[rr][64 + c];
    }
}

// Per (b,k): mean = z[b, idx, :] @ M ; write bias; zero accumulators + cnt.
__global__ __launch_bounds__(64) void k_init(const float* __restrict__ z,
                                             const int* __restrict__ idxs,
                                             const float* __restrict__ M,
                                             const float* __restrict__ IA,
                                             float* __restrict__ out_mean,
                                             float* __restrict__ bias,
                                             float* __restrict__ nk,
                                             float* __restrict__ macc,
                                             int* __restrict__ cnt) {
    int k = blockIdx.x, b = blockIdx.y;
    int l = threadIdx.x;
    int bk = b * KK + k;
    __shared__ float srow[64];
    __shared__ float smean[64];
    int idx = idxs[bk];
    srow[l] = z[((size_t)b * NN + idx) * LL + l];
    __syncthreads();
    float nm = 0.f;
    #pragma unroll 8
    for (int m = 0; m < 64; ++m) nm += srow[m] * M[m * 64 + l];
    out_mean[(size_t)bk * LL + l] = nm;
    smean[l] = nm;
    __syncthreads();
    float cm = 0.f;
    #pragma unroll 8
    for (int m = 0; m < 64; ++m) cm += smean[m] * IA[m * 64 + l];
    float sqm = nm * nm;
    float sqc = cm * cm;
    for (int off = 32; off > 0; off >>= 1) {
        sqm += __shfl_down(sqm, off);
        sqc += __shfl_down(sqc, off);
    }
    if (l == 0) {
        bias[bk] = logf(1.0f / KK) - 0.5f * (sqm + sqc);
        nk[bk] = 0.f;
        if (k == 0) cnt[b] = 0;
    }
    macc[(size_t)bk * LL + l] = 0.f;
}

// Fused EM pass + last-block finalize.
// Phase A (swapped operands): D[comp][zrow] = mean·zᵀ via MFMA; softmax over
// comp = 7 reg-max + 2 shfls per zrow. Phase B: macc via MFMA (A=ptT, B=zT).
// Last finishing block per batch applies M/IA and writes pi/mean/trace/bias.
__global__ __launch_bounds__(256, 2) void k_empass(const float* __restrict__ z,
                                                   float* __restrict__ mean,
                                                   float* __restrict__ bias,
                                                   float* __restrict__ nk,
                                                   float* __restrict__ macc,
                                                   int* __restrict__ cnt,
                                                   const float* __restrict__ M,
                                                   const float* __restrict__ IA,
                                                   float* __restrict__ out_pi,
                                                   float* __restrict__ out_trace) {
    __shared__ __align__(16) unsigned short zhl[2][TILE][ZSB];   // z hi/lo, row-major
    __shared__ __align__(16) unsigned short mhl[2][32][ZSB];     // mean hi/lo, rows 20-31 zero
    __shared__ __align__(16) unsigned short zT[64][ZTS];         // z hi, col-major
    __shared__ __align__(16) unsigned short ptT[32][PTTS];       // posteriors [comp][row], rows 20-31 zero
    __shared__ __align__(16) float bias_s[32];                   // comps >=20: -1e30
    __shared__ float nkred[4][KK];
    __shared__ int isLast;
    int t = threadIdx.x;
    int lane = t & 63;
    int q = t >> 6;             // wave id 0..3, owns zrows q*32..q*32+31
    int ln = lane & 15;
    int lg4 = lane >> 4;        // 0..3
    int s = t & 15;             // col-quad for staging
    int b = blockIdx.y;
    size_t zbase = ((size_t)b * NN + (size_t)blockIdx.x * (TILE * NT)) * LL;

    // stage mean (split hi/lo) + zero pads + bias; zero ptT comp rows 20..31
    for (int i = t; i < KK * LL; i += 256) {
        float f = mean[(size_t)b * KK * LL + i];
        int k = i >> 6, c = i & 63;
        unsigned short h = f2bf(f);
        mhl[0][k][c] = h;
        mhl[1][k][c] = f2bf(f - bf2f(h));
    }
    for (int i = 20 * ZSB + t; i < 32 * ZSB; i += 256) {
        (&mhl[0][0][0])[i] = 0;
        (&mhl[1][0][0])[i] = 0;
    }
    {
        unsigned int* pz = (unsigned int*)&ptT[20][0];
        for (int i = t; i < 6 * PTTS; i += 256) pz[i] = 0;   // 12*PTTS ushorts
    }
    if (t < 32) bias_s[t] = (t < KK) ? bias[b * KK + t] : -1e30f;
    __syncthreads();
    float4 b0 = *(const float4*)&bias_s[lg4 * 4];        // comps lg4*4..+3
    float4 b1 = *(const float4*)&bias_s[16 + lg4 * 4];   // comps 16+lg4*4..+3

    const float4* zg = (const float4*)(z + zbase);
    f32x4 bacc0 = {0.f, 0.f, 0.f, 0.f};
    f32x4 bacc1 = {0.f, 0.f, 0.f, 0.f};
    float nkp0[4] = {0.f, 0.f, 0.f, 0.f};
    float nkp1[4] = {0.f, 0.f, 0.f, 0.f};

    for (int tt = 0; tt < NT; ++tt) {
        if (tt > 0) __syncthreads();   // prev phase-B reads done before overwrite
        // ---- stage: thread loads rows r0,r0+1 x cols 4s..4s+3 ----
        #pragma unroll
        for (int u = 0; u < 4; ++u) {
            int r0 = u * 32 + ((t >> 4) << 1);
            float4 v0 = zg[tt * 2048 + r0 * 16 + s];
            float4 v1 = zg[tt * 2048 + (r0 + 1) * 16 + s];
            unsigned short h0 = f2bf(v0.x), h1 = f2bf(v0.y), h2 = f2bf(v0.z), h3 = f2bf(v0.w);
            unsigned short g0 = f2bf(v1.x), g1 = f2bf(v1.y), g2 = f2bf(v1.z), g3 = f2bf(v1.w);
            *(u16x4*)&zhl[0][r0][4 * s]     = (u16x4){h0, h1, h2, h3};
            *(u16x4*)&zhl[0][r0 + 1][4 * s] = (u16x4){g0, g1, g2, g3};
            *(u16x4*)&zhl[1][r0][4 * s]     = (u16x4){f2bf(v0.x - bf2f(h0)), f2bf(v0.y - bf2f(h1)),
                                                      f2bf(v0.z - bf2f(h2)), f2bf(v0.w - bf2f(h3))};
            *(u16x4*)&zhl[1][r0 + 1][4 * s] = (u16x4){f2bf(v1.x - bf2f(g0)), f2bf(v1.y - bf2f(g1)),
                                                      f2bf(v1.z - bf2f(g2)), f2bf(v1.w - bf2f(g3))};
            *(u16x2*)&zT[4 * s + 0][r0] = (u16x2){h0, g0};
            *(u16x2*)&zT[4 * s + 1][r0] = (u16x2){h1, g1};
            *(u16x2*)&zT[4 * s + 2][r0] = (u16x2){h2, g2};
            *(u16x2*)&zT[4 * s + 3][r0] = (u16x2){h3, g3};
        }
        __syncthreads();

        // ---- phase A: D[comp][zrow] = mean·zᵀ (3-product bf16 split) ----
        f32x4 acc0[2], acc1[2];
        #pragma unroll
        for (int rt = 0; rt < 2; ++rt) {
            acc0[rt] = (f32x4){b0.x, b0.y, b0.z, b0.w};
            acc1[rt] = (f32x4){b1.x, b1.y, b1.z, b1.w};
        }
        #pragma unroll
        for (int ks = 0; ks < 2; ++ks) {
            int kc = ks * 32 + lg4 * 8;
            s16x8 mh0 = *(const s16x8*)&mhl[0][ln][kc];
            s16x8 ml0 = *(const s16x8*)&mhl[1][ln][kc];
            s16x8 mh1 = *(const s16x8*)&mhl[0][16 + ln][kc];
            s16x8 ml1 = *(const s16x8*)&mhl[1][16 + ln][kc];
            #pragma unroll
            for (int rt = 0; rt < 2; ++rt) {
                int zrow = q * 32 + rt * 16 + ln;
                s16x8 zh = *(const s16x8*)&zhl[0][zrow][kc];
                s16x8 zl = *(const s16x8*)&zhl[1][zrow][kc];
                acc0[rt] = MFMA_BF16(mh0, zh, acc0[rt], 0, 0, 0);
                acc0[rt] = MFMA_BF16(ml0, zh, acc0[rt], 0, 0, 0);
                acc0[rt] = MFMA_BF16(mh0, zl, acc0[rt], 0, 0, 0);
                acc1[rt] = MFMA_BF16(mh1, zh, acc1[rt], 0, 0, 0);
                acc1[rt] = MFMA_BF16(ml1, zh, acc1[rt], 0, 0, 0);
                acc1[rt] = MFMA_BF16(mh1, zl, acc1[rt], 0, 0, 0);
            }
        }
        // ---- softmax over comps (regs + 2 shfls per zrow) -> ptT bf16 ----
        #pragma unroll
        for (int rt = 0; rt < 2; ++rt) {
            int zrow = q * 32 + rt * 16 + ln;
            float m = fmaxf(fmaxf(fmaxf(acc0[rt][0], acc0[rt][1]), fmaxf(acc0[rt][2], acc0[rt][3])),
                            fmaxf(fmaxf(acc1[rt][0], acc1[rt][1]), fmaxf(acc1[rt][2], acc1[rt][3])));
            m = fmaxf(m, __shfl_xor(m, 16));
            m = fmaxf(m, __shfl_xor(m, 32));
            float e0[4], e1[4];
            float sm = 0.f;
            #pragma unroll
            for (int j = 0; j < 4; ++j) {
                e0[j] = __expf(acc0[rt][j] - m); sm += e0[j];
                e1[j] = __expf(acc1[rt][j] - m); sm += e1[j];
            }
            sm += __shfl_xor(sm, 16);
            sm += __shfl_xor(sm, 32);
            float inv = 1.0f / sm;
            #pragma unroll
            for (int j = 0; j < 4; ++j) {
                float p = e0[j] * inv;
                nkp0[j] += p;
                ptT[lg4 * 4 + j][zrow] = f2bf(p);
            }
            if (lg4 == 0) {
                #pragma unroll
                for (int j = 0; j < 4; ++j) {
                    float p = e1[j] * inv;
                    nkp1[j] += p;
                    ptT[16 + j][zrow] = f2bf(p);
                }
            }
        }
        __syncthreads();

        // ---- phase B: macc-tile MFMA; wave q -> cols 16q..16q+15 ----
        #pragma unroll
        for (int ch = 0; ch < 4; ++ch) {
            int rr = ch * 32 + lg4 * 8;
            s16x4 zb0 = *(const s16x4*)&zT[q * 16 + ln][rr];
            s16x4 zb1 = *(const s16x4*)&zT[q * 16 + ln][rr + 4];
            s16x8 bfr = (s16x8){zb0[0], zb0[1], zb0[2], zb0[3], zb1[0], zb1[1], zb1[2], zb1[3]};
            s16x8 af0 = *(const s16x8*)&ptT[ln][rr];
            s16x8 af1 = *(const s16x8*)&ptT[16 + ln][rr];
            bacc0 = MFMA_BF16(af0, bfr, bacc0, 0, 0, 0);
            bacc1 = MFMA_BF16(af1, bfr, bacc1, 0, 0, 0);
        }
    }

    // ---- Nk reduce: sum over ln lanes (xor 1,2,4,8), write per-wave ----
    #pragma unroll
    for (int j = 0; j < 4; ++j) {
        nkp0[j] += __shfl_xor(nkp0[j], 1);
        nkp0[j] += __shfl_xor(nkp0[j], 2);
        nkp0[j] += __shfl_xor(nkp0[j], 4);
        nkp0[j] += __shfl_xor(nkp0[j], 8);
    }
    if (ln == 0) {
        #pragma unroll
        for (int j = 0; j < 4; ++j) nkred[q][lg4 * 4 + j] = nkp0[j];
    }
    if (lg4 == 0) {
        #pragma unroll
        for (int j = 0; j < 4; ++j) {
            nkp1[j] += __shfl_xor(nkp1[j], 1);
            nkp1[j] += __shfl_xor(nkp1[j], 2);
            nkp1[j] += __shfl_xor(nkp1[j], 4);
            nkp1[j] += __shfl_xor(nkp1[j], 8);
        }
        if (ln == 0) {
            #pragma unroll
            for (int j = 0; j < 4; ++j) nkred[q][16 + j] = nkp1[j];
        }
    }

    // ---- macc atomics: D col = 16q+ln; D row = lg4*4+reg -> comp ----
    int col = q * 16 + ln;
    #pragma unroll
    for (int reg = 0; reg < 4; ++reg) {
        int comp = lg4 * 4 + reg;
        atomicAdd(&macc[((size_t)b * KK + comp) * LL + col], bacc0[reg]);
    }
    if (lg4 == 0) {
        #pragma unroll
        for (int reg = 0; reg < 4; ++reg)
            atomicAdd(&macc[((size_t)b * KK + 16 + reg) * LL + col], bacc1[reg]);
    }
    __syncthreads();
    if (t < KK) {
        float sum = nkred[0][t] + nkred[1][t] + nkred[2][t] + nkred[3][t];
        atomicAdd(&nk[b * KK + t], sum);
    }
    __syncthreads();            // all this block's atomics retired
    if (t == 0) {
        __threadfence();
        int old = atomicAdd(&cnt[b], 1);
        isLast = (old == CHUNKS - 1) ? 1 : 0;
    }
    __syncthreads();
    if (!isLast) return;

    // ---- finalize batch b (this block only): old k_final for 20 comps ----
    // wave q handles comps q, q+4, ..., q+16; scratch reuses zhl region.
    float* fs = (float*)&zhl[0][0][0];
    float* sraw = fs + q * 160;
    float* smean = sraw + 64;
    int l = lane;
    #pragma unroll
    for (int kc5 = 0; kc5 < 5; ++kc5) {
        int comp = kc5 * 4 + q;
        int bk = b * KK + comp;
        size_t mb = (size_t)bk * LL;
        float nkv = 0.f;
        if (l == 0) nkv = atomicExch(&nk[bk], 0.f);
        nkv = __shfl(nkv, 0);
        float nkc = fmaxf(nkv, 1e-22f);
        float raw = atomicExch(&macc[mb + l], 0.f) / nkc;
        sraw[l] = raw;
        float nm = 0.f;
        #pragma unroll 8
        for (int m = 0; m < 64; ++m) nm += sraw[m] * M[m * 64 + l];
        mean[mb + l] = nm;
        smean[l] = nm;
        float cm = 0.f;
        #pragma unroll 8
        for (int m = 0; m < 64; ++m) cm += smean[m] * IA[m * 64 + l];
        float sqm = nm * nm;
        float sqc = cm * cm;
        #pragma unroll
        for (int off = 32; off > 0; off >>= 1) {
            sqm += __shfl_down(sqm, off);
            sqc += __shfl_down(sqc, off);
        }
        if (l == 0) {
            float pi = nkc * (1.0f / NN);
            bias[bk] = logf(pi) - 0.5f * (sqm + sqc);
            out_pi[bk] = pi;
            out_trace[bk] = 1.0f;
        }
    }
    if (t == 0) cnt[b] = 0;     // self-clean for next launch / graph replay
}

extern "C" void kernel_launch(void* const* d_in, const int* in_sizes, int n_in,
                              void* d_out, int out_size, void* d_ws, size_t ws_size,
                              hipStream_t stream) {
    const float* z = (const float*)d_in[0];
    const float* A = (const float*)d_in[1];
    const int* idxs = (const int*)d_in[2];

    float* out_pi = (float*)d_out;
    float* out_mean = out_pi + BB * KK;
    float* out_trace = out_mean + (size_t)BB * KK * LL;

    float* ws = (float*)d_ws;
    float* IA = ws;
    float* M = ws + 4096;
    float* bias = ws + 8192;
    float* nk = ws + 9472;
    float* macc = ws + 10752;
    int* cnt = (int*)(ws + 92672);

    k_setup<<<1, 256, 0, stream>>>(A, IA, M);
    k_init<<<dim3(KK, BB), 64, 0, stream>>>(z, idxs, M, IA, out_mean, bias, nk, macc, cnt);
    for (int it = 0; it < 5; ++it) {
        k_empass<<<dim3(CHUNKS, BB), 256, 0, stream>>>(z, out_mean, bias, nk, macc,
                                                       cnt, M, IA, out_pi, out_trace);
    }
}

// Round 9
// 335.020 us; speedup vs baseline: 1.1262x; 1.1262x over previous
//
#include <hip/hip_runtime.h>
#include <math.h>

#define BB 64
#define NN 8192
#define LL 64
#define KK 20
#define TILE 128
#define NT 8        // tiles per block
#define CHUNKS 8    // blocks per batch entry: CHUNKS*NT*TILE == NN (512 blocks = 2/CU)
#define ZSB 72      // zhl/mhl row stride (ushorts): 144 B (16B-multiple)
#define ZTS 140     // zT row stride (ushorts): 280 B (8B-multiple, odd granules)
#define PTTS 136    // ptT row stride (ushorts): 272 B (16B-multiple)
#define NSS 68      // Newton-Schulz matrix stride (floats): 272 B

typedef float f32x4 __attribute__((ext_vector_type(4)));
typedef short s16x8 __attribute__((ext_vector_type(8)));
typedef short s16x4 __attribute__((ext_vector_type(4)));
typedef unsigned short u16x4 __attribute__((ext_vector_type(4)));
typedef unsigned short u16x2 __attribute__((ext_vector_type(2)));

#define MFMA_BF16 __builtin_amdgcn_mfma_f32_16x16x32_bf16

__device__ __forceinline__ unsigned short f2bf(float f) {   // RNE fp32->bf16
    unsigned int u = __float_as_uint(f);
    u += 0x7fffu + ((u >> 16) & 1u);
    return (unsigned short)(u >> 16);
}
__device__ __forceinline__ float bf2f(unsigned short h) {
    return __uint_as_float(((unsigned int)h) << 16);
}

// ---------------------------------------------------------------------------
// ws layout (floats): IA @0, M @4096, bias @8192, nk @9472, macc @10752,
// cnt(int) @92672. Requires ws_size >= 370,944 B.
// ---------------------------------------------------------------------------

// IA = I - A ; M = inv(S), S = I + IA·IAᵀ, via Newton-Schulz:
// X_{k+1} = X_k (2I - S X_k).  S SPD with λmin >= 1 (I + PSD); X0 = a·I with
// a = 2/(1+||S||_inf) gives residual ratio (c-1)/(c+1) < 1 → 8 iters ≡ ρ^256,
// fully converged to fp32 floor. All iterates symmetric → row-major float4
// reads only. ~18 barriers total vs 65 serial Gauss-Jordan pivots.
__global__ __launch_bounds__(256) void k_setup(const float* __restrict__ A,
                                               float* __restrict__ IA,
                                               float* __restrict__ M) {
    __shared__ __align__(16) float sS[64][NSS];
    __shared__ __align__(16) float sXa[64][NSS];
    __shared__ __align__(16) float sXb[64][NSS];
    __shared__ __align__(16) float sT[64][NSS];   // iaT during build, then T
    __shared__ float rowsum[64];
    __shared__ float alpha_s;
    int t = threadIdx.x;
    int r0 = (t >> 4) << 2;     // 4x4 block decomposition, used throughout
    int c0 = (t & 15) << 2;

    for (int i = t; i < 4096; i += 256) {
        int r = i >> 6, c = i & 63;
        float v = (r == c ? 1.0f : 0.0f) - A[i];
        IA[i] = v;
        sT[c][r] = v;           // iaT
    }
    __syncthreads();
    {   // S = I + IA·IAᵀ : S[r][c] = δ + Σ_l iaT[l][r]·iaT[l][c]
        float s[4][4];
        #pragma unroll
        for (int a = 0; a < 4; ++a)
            #pragma unroll
            for (int b = 0; b < 4; ++b) s[a][b] = 0.f;
        #pragma unroll 4
        for (int l = 0; l < 64; ++l) {
            float4 u = *(const float4*)&sT[l][r0];
            float4 v = *(const float4*)&sT[l][c0];
            float uu[4] = {u.x, u.y, u.z, u.w};
            float vv[4] = {v.x, v.y, v.z, v.w};
            #pragma unroll
            for (int a = 0; a < 4; ++a)
                #pragma unroll
                for (int b = 0; b < 4; ++b) s[a][b] += uu[a] * vv[b];
        }
        #pragma unroll
        for (int a = 0; a < 4; ++a) {
            int r = r0 + a;
            float4 w;
            w.x = s[a][0] + (r == c0 + 0 ? 1.f : 0.f);
            w.y = s[a][1] + (r == c0 + 1 ? 1.f : 0.f);
            w.z = s[a][2] + (r == c0 + 2 ? 1.f : 0.f);
            w.w = s[a][3] + (r == c0 + 3 ? 1.f : 0.f);
            *(float4*)&sS[r][c0] = w;
        }
    }
    __syncthreads();
    if (t < 64) {               // ||S||_inf
        float sm = 0.f;
        #pragma unroll 4
        for (int c = 0; c < 64; c += 4) {
            float4 v = *(const float4*)&sS[t][c];
            sm += fabsf(v.x) + fabsf(v.y) + fabsf(v.z) + fabsf(v.w);
        }
        rowsum[t] = sm;
    }
    __syncthreads();
    if (t == 0) {
        float mx = rowsum[0];
        for (int i = 1; i < 64; ++i) mx = fmaxf(mx, rowsum[i]);
        alpha_s = 2.0f / (1.0f + mx);
    }
    __syncthreads();
    float alpha = alpha_s;
    for (int i = t; i < 4096; i += 256) {
        int r = i >> 6, c = i & 63;
        sXa[r][c] = (r == c) ? alpha : 0.f;
    }
    __syncthreads();

    float* X  = &sXa[0][0];
    float* Xn = &sXb[0][0];
    for (int it = 0; it < 8; ++it) {
        // T = S·X  (S, X symmetric → row reads: S[r][k]=S[k][r], X[k][c])
        {
            float s[4][4];
            #pragma unroll
            for (int a = 0; a < 4; ++a)
                #pragma unroll
                for (int b = 0; b < 4; ++b) s[a][b] = 0.f;
            #pragma unroll 4
            for (int k = 0; k < 64; ++k) {
                float4 u = *(const float4*)&sS[k][r0];
                float4 v = *(const float4*)&X[k * NSS + c0];
                float uu[4] = {u.x, u.y, u.z, u.w};
                float vv[4] = {v.x, v.y, v.z, v.w};
                #pragma unroll
                for (int a = 0; a < 4; ++a)
                    #pragma unroll
                    for (int b = 0; b < 4; ++b) s[a][b] += uu[a] * vv[b];
            }
            #pragma unroll
            for (int a = 0; a < 4; ++a)
                *(float4*)&sT[r0 + a][c0] = (float4){s[a][0], s[a][1], s[a][2], s[a][3]};
        }
        __syncthreads();
        // Xn = 2X − X·T  (X sym → X[r][k] = X[k][r] row reads)
        {
            float s[4][4];
            #pragma unroll
            for (int a = 0; a < 4; ++a)
                #pragma unroll
                for (int b = 0; b < 4; ++b) s[a][b] = 0.f;
            #pragma unroll 4
            for (int k = 0; k < 64; ++k) {
                float4 u = *(const float4*)&X[k * NSS + r0];
                float4 v = *(const float4*)&sT[k][c0];
                float uu[4] = {u.x, u.y, u.z, u.w};
                float vv[4] = {v.x, v.y, v.z, v.w};
                #pragma unroll
                for (int a = 0; a < 4; ++a)
                    #pragma unroll
                    for (int b = 0; b < 4; ++b) s[a][b] += uu[a] * vv[b];
            }
            #pragma unroll
            for (int a = 0; a < 4; ++a) {
                float4 xo = *(const float4*)&X[(r0 + a) * NSS + c0];
                float4 w;
                w.x = 2.f * xo.x - s[a][0];
                w.y = 2.f * xo.y - s[a][1];
                w.z = 2.f * xo.z - s[a][2];
                w.w = 2.f * xo.w - s[a][3];
                *(float4*)&Xn[(r0 + a) * NSS + c0] = w;
            }
        }
        __syncthreads();
        float* tmp = X; X = Xn; Xn = tmp;
    }
    for (int i = t; i < 4096; i += 256)
        M[i] = X[(i >> 6) * NSS + (i & 63)];
}

// Per (b,k): mean = z[b, idx, :] @ M ; write bias; zero accumulators + cnt.
__global__ __launch_bounds__(64) void k_init(const float* __restrict__ z,
                                             const int* __restrict__ idxs,
                                             const float* __restrict__ M,
                                             const float* __restrict__ IA,
                                             float* __restrict__ out_mean,
                                             float* __restrict__ bias,
                                             float* __restrict__ nk,
                                             float* __restrict__ macc,
                                             int* __restrict__ cnt) {
    int k = blockIdx.x, b = blockIdx.y;
    int l = threadIdx.x;
    int bk = b * KK + k;
    __shared__ float srow[64];
    __shared__ float smean[64];
    int idx = idxs[bk];
    srow[l] = z[((size_t)b * NN + idx) * LL + l];
    __syncthreads();
    float nm = 0.f;
    #pragma unroll 8
    for (int m = 0; m < 64; ++m) nm += srow[m] * M[m * 64 + l];
    out_mean[(size_t)bk * LL + l] = nm;
    smean[l] = nm;
    __syncthreads();
    float cm = 0.f;
    #pragma unroll 8
    for (int m = 0; m < 64; ++m) cm += smean[m] * IA[m * 64 + l];
    float sqm = nm * nm;
    float sqc = cm * cm;
    for (int off = 32; off > 0; off >>= 1) {
        sqm += __shfl_down(sqm, off);
        sqc += __shfl_down(sqc, off);
    }
    if (l == 0) {
        bias[bk] = logf(1.0f / KK) - 0.5f * (sqm + sqc);
        nk[bk] = 0.f;
        if (k == 0) cnt[b] = 0;
    }
    macc[(size_t)bk * LL + l] = 0.f;
}

// Fused EM pass, deep-pipelined:
//  - wave-private staging: wave q owns zhl rows [32q,32q+32) (phase-A slice)
//    and zT rows [16q,16q+16)=global cols (phase-B slice is read cross... no:
//    zT written cross-col by ln groups, read by all waves -> zT write after bar2.
//  - tile t+1 global loads issued at tile top (hidden under A+softmax+B);
//    zhl writes overlap phase B (zhl untouched by B); zT writes after bar2.
//  - 2 barriers/tile; branchless softmax (pad comps bias=-1e30 -> exp=0).
//  - mhl MFMA fragments hoisted to registers once (read-only all tiles).
__global__ __launch_bounds__(256, 2) void k_empass(const float* __restrict__ z,
                                                   float* __restrict__ mean,
                                                   float* __restrict__ bias,
                                                   float* __restrict__ nk,
                                                   float* __restrict__ macc,
                                                   int* __restrict__ cnt,
                                                   const float* __restrict__ M,
                                                   const float* __restrict__ IA,
                                                   float* __restrict__ out_pi,
                                                   float* __restrict__ out_trace) {
    __shared__ __align__(16) unsigned short zhl[2][TILE][ZSB];   // z hi/lo row-major
    __shared__ __align__(16) unsigned short mhl[2][32][ZSB];     // mean hi/lo, rows 20-31 zero
    __shared__ __align__(16) unsigned short zT[64][ZTS];         // z hi col-major
    __shared__ __align__(16) unsigned short ptT[32][PTTS];       // posteriors [comp][zrow]
    __shared__ __align__(16) float bias_s[32];                   // comps >=20: -1e30
    __shared__ float nkred[4][KK];
    __shared__ int isLast;
    int t = threadIdx.x;
    int lane = t & 63;
    int q = t >> 6;             // wave id 0..3, owns zrows [32q, 32q+32)
    int ln = lane & 15;
    int lg4 = lane >> 4;        // 0..3
    int b = blockIdx.y;
    size_t zbase = ((size_t)b * NN + (size_t)blockIdx.x * (TILE * NT)) * LL;
    int rbase = 32 * q + 8 * lg4;   // staging row base (2-row pairs, u=0..3)

    // ---- stage mean (hi/lo split) + zero pad rows + bias ----
    for (int i = t; i < KK * LL; i += 256) {
        float f = mean[(size_t)b * KK * LL + i];
        int k = i >> 6, c = i & 63;
        unsigned short h = f2bf(f);
        mhl[0][k][c] = h;
        mhl[1][k][c] = f2bf(f - bf2f(h));
    }
    for (int i = 20 * ZSB + t; i < 32 * ZSB; i += 256) {
        (&mhl[0][0][0])[i] = 0;
        (&mhl[1][0][0])[i] = 0;
    }
    if (t < 32) bias_s[t] = (t < KK) ? bias[b * KK + t] : -1e30f;
    __syncthreads();
    float4 b0 = *(const float4*)&bias_s[lg4 * 4];
    float4 b1 = *(const float4*)&bias_s[16 + lg4 * 4];
    // hoist mean fragments (constant across tiles): [ks*4 + {mh0,ml0,mh1,ml1}]
    s16x8 mf[8];
    #pragma unroll
    for (int ks = 0; ks < 2; ++ks) {
        int kc = ks * 32 + lg4 * 8;
        mf[ks * 4 + 0] = *(const s16x8*)&mhl[0][ln][kc];
        mf[ks * 4 + 1] = *(const s16x8*)&mhl[1][ln][kc];
        mf[ks * 4 + 2] = *(const s16x8*)&mhl[0][16 + ln][kc];
        mf[ks * 4 + 3] = *(const s16x8*)&mhl[1][16 + ln][kc];
    }

    const float4* zg = (const float4*)(z + zbase);
    float4 pf[8];

#define LOADT(tt)                                                              \
    {                                                                          \
        _Pragma("unroll")                                                      \
        for (int u = 0; u < 4; ++u) {                                          \
            int r0_ = rbase + 2 * u;                                           \
            pf[2 * u]     = zg[(size_t)(tt) * 2048 + r0_ * 16 + ln];           \
            pf[2 * u + 1] = zg[(size_t)(tt) * 2048 + (r0_ + 1) * 16 + ln];     \
        }                                                                      \
    }
#define WRITE_ZHL                                                              \
    {                                                                          \
        _Pragma("unroll")                                                      \
        for (int u = 0; u < 4; ++u) {                                          \
            int r0_ = rbase + 2 * u;                                           \
            float4 v0 = pf[2 * u], v1 = pf[2 * u + 1];                         \
            unsigned short h0 = f2bf(v0.x), h1 = f2bf(v0.y),                   \
                           h2 = f2bf(v0.z), h3 = f2bf(v0.w);                   \
            unsigned short g0 = f2bf(v1.x), g1 = f2bf(v1.y),                   \
                           g2 = f2bf(v1.z), g3 = f2bf(v1.w);                   \
            *(u16x4*)&zhl[0][r0_][4 * ln]     = (u16x4){h0, h1, h2, h3};       \
            *(u16x4*)&zhl[0][r0_ + 1][4 * ln] = (u16x4){g0, g1, g2, g3};       \
            *(u16x4*)&zhl[1][r0_][4 * ln] =                                    \
                (u16x4){f2bf(v0.x - bf2f(h0)), f2bf(v0.y - bf2f(h1)),          \
                        f2bf(v0.z - bf2f(h2)), f2bf(v0.w - bf2f(h3))};         \
            *(u16x4*)&zhl[1][r0_ + 1][4 * ln] =                                \
                (u16x4){f2bf(v1.x - bf2f(g0)), f2bf(v1.y - bf2f(g1)),          \
                        f2bf(v1.z - bf2f(g2)), f2bf(v1.w - bf2f(g3))};         \
        }                                                                      \
    }
#define WRITE_ZT                                                               \
    {                                                                          \
        _Pragma("unroll")                                                      \
        for (int u = 0; u < 4; ++u) {                                          \
            int r0_ = rbase + 2 * u;                                           \
            float4 v0 = pf[2 * u], v1 = pf[2 * u + 1];                         \
            *(u16x2*)&zT[4 * ln + 0][r0_] = (u16x2){f2bf(v0.x), f2bf(v1.x)};   \
            *(u16x2*)&zT[4 * ln + 1][r0_] = (u16x2){f2bf(v0.y), f2bf(v1.y)};   \
            *(u16x2*)&zT[4 * ln + 2][r0_] = (u16x2){f2bf(v0.z), f2bf(v1.z)};   \
            *(u16x2*)&zT[4 * ln + 3][r0_] = (u16x2){f2bf(v0.w), f2bf(v1.w)};   \
        }                                                                      \
    }

    // prologue: stage tile 0
    LOADT(0);
    WRITE_ZHL;
    WRITE_ZT;
    __syncthreads();

    f32x4 bacc0 = {0.f, 0.f, 0.f, 0.f};
    f32x4 bacc1 = {0.f, 0.f, 0.f, 0.f};
    float nkp0[4] = {0.f, 0.f, 0.f, 0.f};
    float nkp1[4] = {0.f, 0.f, 0.f, 0.f};

    for (int tt = 0; tt < NT; ++tt) {
        if (tt + 1 < NT) LOADT(tt + 1);      // issue early; consumed post-B

        // ---- phase A: D[comp][zrow] = mean·zᵀ (3-product bf16 split) ----
        f32x4 acc0[2], acc1[2];
        #pragma unroll
        for (int rt = 0; rt < 2; ++rt) {
            acc0[rt] = (f32x4){b0.x, b0.y, b0.z, b0.w};
            acc1[rt] = (f32x4){b1.x, b1.y, b1.z, b1.w};
        }
        #pragma unroll
        for (int ks = 0; ks < 2; ++ks) {
            int kc = ks * 32 + lg4 * 8;
            #pragma unroll
            for (int rt = 0; rt < 2; ++rt) {
                int zrow = q * 32 + rt * 16 + ln;
                s16x8 zh = *(const s16x8*)&zhl[0][zrow][kc];
                s16x8 zl = *(const s16x8*)&zhl[1][zrow][kc];
                acc0[rt] = MFMA_BF16(mf[ks * 4 + 0], zh, acc0[rt], 0, 0, 0);
                acc0[rt] = MFMA_BF16(mf[ks * 4 + 1], zh, acc0[rt], 0, 0, 0);
                acc0[rt] = MFMA_BF16(mf[ks * 4 + 0], zl, acc0[rt], 0, 0, 0);
                acc1[rt] = MFMA_BF16(mf[ks * 4 + 2], zh, acc1[rt], 0, 0, 0);
                acc1[rt] = MFMA_BF16(mf[ks * 4 + 3], zh, acc1[rt], 0, 0, 0);
                acc1[rt] = MFMA_BF16(mf[ks * 4 + 2], zl, acc1[rt], 0, 0, 0);
            }
        }
        // ---- softmax over comps, branchless (pad comps give exp(-1e30)=0) ----
        #pragma unroll
        for (int rt = 0; rt < 2; ++rt) {
            int zrow = q * 32 + rt * 16 + ln;
            float m = fmaxf(fmaxf(fmaxf(acc0[rt][0], acc0[rt][1]), fmaxf(acc0[rt][2], acc0[rt][3])),
                            fmaxf(fmaxf(acc1[rt][0], acc1[rt][1]), fmaxf(acc1[rt][2], acc1[rt][3])));
            m = fmaxf(m, __shfl_xor(m, 16));
            m = fmaxf(m, __shfl_xor(m, 32));
            float e0[4], e1[4];
            float sm = 0.f;
            #pragma unroll
            for (int j = 0; j < 4; ++j) {
                e0[j] = __expf(acc0[rt][j] - m); sm += e0[j];
                e1[j] = __expf(acc1[rt][j] - m); sm += e1[j];
            }
            sm += __shfl_xor(sm, 16);
            sm += __shfl_xor(sm, 32);
            float inv = 1.0f / sm;
            #pragma unroll
            for (int j = 0; j < 4; ++j) {
                float p0 = e0[j] * inv;
                float p1 = e1[j] * inv;
                nkp0[j] += p0;
                nkp1[j] += p1;
                ptT[lg4 * 4 + j][zrow] = f2bf(p0);
                ptT[16 + lg4 * 4 + j][zrow] = f2bf(p1);
            }
        }
        __syncthreads();    // bar1: ptT complete

        // ---- phase B: macc-tile MFMA; wave q -> cols 16q..16q+15 ----
        #pragma unroll
        for (int ch = 0; ch < 4; ++ch) {
            int rr = ch * 32 + lg4 * 8;
            s16x4 zb0 = *(const s16x4*)&zT[q * 16 + ln][rr];
            s16x4 zb1 = *(const s16x4*)&zT[q * 16 + ln][rr + 4];
            s16x8 bfr = (s16x8){zb0[0], zb0[1], zb0[2], zb0[3], zb1[0], zb1[1], zb1[2], zb1[3]};
            s16x8 af0 = *(const s16x8*)&ptT[ln][rr];
            s16x8 af1 = *(const s16x8*)&ptT[16 + ln][rr];
            bacc0 = MFMA_BF16(af0, bfr, bacc0, 0, 0, 0);
            bacc1 = MFMA_BF16(af1, bfr, bacc1, 0, 0, 0);
        }
        if (tt + 1 < NT) WRITE_ZHL;   // zhl wave-private; B doesn't touch zhl
        __syncthreads();    // bar2: all B-reads of zT/ptT done
        if (tt + 1 < NT) WRITE_ZT;    // completes before bar1 of next tile
    }

    // ---- Nk reduce: sum over ln lanes (xor 1,2,4,8) ----
    #pragma unroll
    for (int j = 0; j < 4; ++j) {
        nkp0[j] += __shfl_xor(nkp0[j], 1);
        nkp0[j] += __shfl_xor(nkp0[j], 2);
        nkp0[j] += __shfl_xor(nkp0[j], 4);
        nkp0[j] += __shfl_xor(nkp0[j], 8);
        nkp1[j] += __shfl_xor(nkp1[j], 1);
        nkp1[j] += __shfl_xor(nkp1[j], 2);
        nkp1[j] += __shfl_xor(nkp1[j], 4);
        nkp1[j] += __shfl_xor(nkp1[j], 8);
    }
    if (ln == 0) {
        #pragma unroll
        for (int j = 0; j < 4; ++j) nkred[q][lg4 * 4 + j] = nkp0[j];
        if (lg4 == 0) {
            #pragma unroll
            for (int j = 0; j < 4; ++j) nkred[q][16 + j] = nkp1[j];
        }
    }

    // ---- macc atomics: D col = 16q+ln; D row = lg4*4+reg -> comp ----
    int col = q * 16 + ln;
    #pragma unroll
    for (int reg = 0; reg < 4; ++reg) {
        int comp = lg4 * 4 + reg;
        atomicAdd(&macc[((size_t)b * KK + comp) * LL + col], bacc0[reg]);
    }
    if (lg4 == 0) {
        #pragma unroll
        for (int reg = 0; reg < 4; ++reg)
            atomicAdd(&macc[((size_t)b * KK + 16 + reg) * LL + col], bacc1[reg]);
    }
    __syncthreads();
    if (t < KK) {
        float sum = nkred[0][t] + nkred[1][t] + nkred[2][t] + nkred[3][t];
        atomicAdd(&nk[b * KK + t], sum);
    }
    __syncthreads();            // all this block's atomics retired
    if (t == 0) {
        __threadfence();
        int old = atomicAdd(&cnt[b], 1);
        isLast = (old == CHUNKS - 1) ? 1 : 0;
    }
    __syncthreads();
    if (!isLast) return;

    // ---- finalize batch b (last block only) ----
    float* fs = (float*)&zhl[0][0][0];
    float* sraw = fs + q * 160;
    float* smean = sraw + 64;
    int l = lane;
    #pragma unroll
    for (int kc5 = 0; kc5 < 5; ++kc5) {
        int comp = kc5 * 4 + q;
        int bk = b * KK + comp;
        size_t mb = (size_t)bk * LL;
        float nkv = 0.f;
        if (l == 0) nkv = atomicExch(&nk[bk], 0.f);
        nkv = __shfl(nkv, 0);
        float nkc = fmaxf(nkv, 1e-22f);
        float raw = atomicExch(&macc[mb + l], 0.f) / nkc;
        sraw[l] = raw;
        float nm = 0.f;
        #pragma unroll 8
        for (int m = 0; m < 64; ++m) nm += sraw[m] * M[m * 64 + l];
        mean[mb + l] = nm;
        smean[l] = nm;
        float cm = 0.f;
        #pragma unroll 8
        for (int m = 0; m < 64; ++m) cm += smean[m] * IA[m * 64 + l];
        float sqm = nm * nm;
        float sqc = cm * cm;
        #pragma unroll
        for (int off = 32; off > 0; off >>= 1) {
            sqm += __shfl_down(sqm, off);
            sqc += __shfl_down(sqc, off);
        }
        if (l == 0) {
            float pi = nkc * (1.0f / NN);
            bias[bk] = logf(pi) - 0.5f * (sqm + sqc);
            out_pi[bk] = pi;
            out_trace[bk] = 1.0f;
        }
    }
    if (t == 0) cnt[b] = 0;
#undef LOADT
#undef WRITE_ZHL
#undef WRITE_ZT
}

extern "C" void kernel_launch(void* const* d_in, const int* in_sizes, int n_in,
                              void* d_out, int out_size, void* d_ws, size_t ws_size,
                              hipStream_t stream) {
    const float* z = (const float*)d_in[0];
    const float* A = (const float*)d_in[1];
    const int* idxs = (const int*)d_in[2];

    float* out_pi = (float*)d_out;
    float* out_mean = out_pi + BB * KK;
    float* out_trace = out_mean + (size_t)BB * KK * LL;

    float* ws = (float*)d_ws;
    float* IA = ws;
    float* M = ws + 4096;
    float* bias = ws + 8192;
    float* nk = ws + 9472;
    float* macc = ws + 10752;
    int* cnt = (int*)(ws + 92672);

    k_setup<<<1, 256, 0, stream>>>(A, IA, M);
    k_init<<<dim3(KK, BB), 64, 0, stream>>>(z, idxs, M, IA, out_mean, bias, nk, macc, cnt);
    for (int it = 0; it < 5; ++it) {
        k_empass<<<dim3(CHUNKS, BB), 256, 0, stream>>>(z, out_mean, bias, nk, macc,
                                                       cnt, M, IA, out_pi, out_trace);
    }
}

// Round 10
// 306.688 us; speedup vs baseline: 1.2302x; 1.0924x over previous
//
#include <hip/hip_runtime.h>
#include <math.h>

#define BB 64
#define NN 8192
#define LL 64
#define KK 20
#define TILE 128
#define NT 8        // tiles per block
#define CHUNKS 8    // blocks per batch entry: CHUNKS*NT*TILE == NN (512 blocks, all resident)
#define ZSB 72      // mhl row stride (ushorts)
#define ZTS 136     // zT row stride (ushorts): 272 B, 16B-aligned b128 reads
#define PTTS 136    // ptT row stride (ushorts): 272 B
#define NSS 68      // Newton-Schulz matrix stride (floats)

typedef float f32x4 __attribute__((ext_vector_type(4)));
typedef short s16x8 __attribute__((ext_vector_type(8)));

#define MFMA_BF16 __builtin_amdgcn_mfma_f32_16x16x32_bf16

__device__ __forceinline__ unsigned short f2bf(float f) {   // RNE fp32->bf16
    unsigned int u = __float_as_uint(f);
    u += 0x7fffu + ((u >> 16) & 1u);
    return (unsigned short)(u >> 16);
}
__device__ __forceinline__ float bf2f(unsigned short h) {
    return __uint_as_float(((unsigned int)h) << 16);
}

// ---------------------------------------------------------------------------
// ws layout (floats): IA @0, M @4096, bias @8192, nk @9472, macc @10752,
// cnt(int) @92672. Requires ws_size >= 370,944 B.
// ---------------------------------------------------------------------------

// IA = I - A ; M = inv(S), S = I + IA·IAᵀ, Newton-Schulz (8 iters, SPD).
__global__ __launch_bounds__(256) void k_setup(const float* __restrict__ A,
                                               float* __restrict__ IA,
                                               float* __restrict__ M) {
    __shared__ __align__(16) float sS[64][NSS];
    __shared__ __align__(16) float sXa[64][NSS];
    __shared__ __align__(16) float sXb[64][NSS];
    __shared__ __align__(16) float sT[64][NSS];   // iaT during build, then T
    __shared__ float rowsum[64];
    __shared__ float alpha_s;
    int t = threadIdx.x;
    int r0 = (t >> 4) << 2;
    int c0 = (t & 15) << 2;

    for (int i = t; i < 4096; i += 256) {
        int r = i >> 6, c = i & 63;
        float v = (r == c ? 1.0f : 0.0f) - A[i];
        IA[i] = v;
        sT[c][r] = v;
    }
    __syncthreads();
    {
        float s[4][4];
        #pragma unroll
        for (int a = 0; a < 4; ++a)
            #pragma unroll
            for (int b = 0; b < 4; ++b) s[a][b] = 0.f;
        #pragma unroll 4
        for (int l = 0; l < 64; ++l) {
            float4 u = *(const float4*)&sT[l][r0];
            float4 v = *(const float4*)&sT[l][c0];
            float uu[4] = {u.x, u.y, u.z, u.w};
            float vv[4] = {v.x, v.y, v.z, v.w};
            #pragma unroll
            for (int a = 0; a < 4; ++a)
                #pragma unroll
                for (int b = 0; b < 4; ++b) s[a][b] += uu[a] * vv[b];
        }
        #pragma unroll
        for (int a = 0; a < 4; ++a) {
            int r = r0 + a;
            float4 w;
            w.x = s[a][0] + (r == c0 + 0 ? 1.f : 0.f);
            w.y = s[a][1] + (r == c0 + 1 ? 1.f : 0.f);
            w.z = s[a][2] + (r == c0 + 2 ? 1.f : 0.f);
            w.w = s[a][3] + (r == c0 + 3 ? 1.f : 0.f);
            *(float4*)&sS[r][c0] = w;
        }
    }
    __syncthreads();
    if (t < 64) {
        float sm = 0.f;
        #pragma unroll 4
        for (int c = 0; c < 64; c += 4) {
            float4 v = *(const float4*)&sS[t][c];
            sm += fabsf(v.x) + fabsf(v.y) + fabsf(v.z) + fabsf(v.w);
        }
        rowsum[t] = sm;
    }
    __syncthreads();
    if (t == 0) {
        float mx = rowsum[0];
        for (int i = 1; i < 64; ++i) mx = fmaxf(mx, rowsum[i]);
        alpha_s = 2.0f / (1.0f + mx);
    }
    __syncthreads();
    float alpha = alpha_s;
    for (int i = t; i < 4096; i += 256) {
        int r = i >> 6, c = i & 63;
        sXa[r][c] = (r == c) ? alpha : 0.f;
    }
    __syncthreads();

    float* X  = &sXa[0][0];
    float* Xn = &sXb[0][0];
    for (int it = 0; it < 8; ++it) {
        {
            float s[4][4];
            #pragma unroll
            for (int a = 0; a < 4; ++a)
                #pragma unroll
                for (int b = 0; b < 4; ++b) s[a][b] = 0.f;
            #pragma unroll 4
            for (int k = 0; k < 64; ++k) {
                float4 u = *(const float4*)&sS[k][r0];
                float4 v = *(const float4*)&X[k * NSS + c0];
                float uu[4] = {u.x, u.y, u.z, u.w};
                float vv[4] = {v.x, v.y, v.z, v.w};
                #pragma unroll
                for (int a = 0; a < 4; ++a)
                    #pragma unroll
                    for (int b = 0; b < 4; ++b) s[a][b] += uu[a] * vv[b];
            }
            #pragma unroll
            for (int a = 0; a < 4; ++a)
                *(float4*)&sT[r0 + a][c0] = (float4){s[a][0], s[a][1], s[a][2], s[a][3]};
        }
        __syncthreads();
        {
            float s[4][4];
            #pragma unroll
            for (int a = 0; a < 4; ++a)
                #pragma unroll
                for (int b = 0; b < 4; ++b) s[a][b] = 0.f;
            #pragma unroll 4
            for (int k = 0; k < 64; ++k) {
                float4 u = *(const float4*)&X[k * NSS + r0];
                float4 v = *(const float4*)&sT[k][c0];
                float uu[4] = {u.x, u.y, u.z, u.w};
                float vv[4] = {v.x, v.y, v.z, v.w};
                #pragma unroll
                for (int a = 0; a < 4; ++a)
                    #pragma unroll
                    for (int b = 0; b < 4; ++b) s[a][b] += uu[a] * vv[b];
            }
            #pragma unroll
            for (int a = 0; a < 4; ++a) {
                float4 xo = *(const float4*)&X[(r0 + a) * NSS + c0];
                float4 w;
                w.x = 2.f * xo.x - s[a][0];
                w.y = 2.f * xo.y - s[a][1];
                w.z = 2.f * xo.z - s[a][2];
                w.w = 2.f * xo.w - s[a][3];
                *(float4*)&Xn[(r0 + a) * NSS + c0] = w;
            }
        }
        __syncthreads();
        float* tmp = X; X = Xn; Xn = tmp;
    }
    for (int i = t; i < 4096; i += 256)
        M[i] = X[(i >> 6) * NSS + (i & 63)];
}

// Per (b,k): mean = z[b, idx, :] @ M ; write bias; zero accumulators + cnt.
__global__ __launch_bounds__(64) void k_init(const float* __restrict__ z,
                                             const int* __restrict__ idxs,
                                             const float* __restrict__ M,
                                             const float* __restrict__ IA,
                                             float* __restrict__ out_mean,
                                             float* __restrict__ bias,
                                             float* __restrict__ nk,
                                             float* __restrict__ macc,
                                             int* __restrict__ cnt) {
    int k = blockIdx.x, b = blockIdx.y;
    int l = threadIdx.x;
    int bk = b * KK + k;
    __shared__ float srow[64];
    __shared__ float smean[64];
    int idx = idxs[bk];
    srow[l] = z[((size_t)b * NN + idx) * LL + l];
    __syncthreads();
    float nm = 0.f;
    #pragma unroll 8
    for (int m = 0; m < 64; ++m) nm += srow[m] * M[m * 64 + l];
    out_mean[(size_t)bk * LL + l] = nm;
    smean[l] = nm;
    __syncthreads();
    float cm = 0.f;
    #pragma unroll 8
    for (int m = 0; m < 64; ++m) cm += smean[m] * IA[m * 64 + l];
    float sqm = nm * nm;
    float sqc = cm * cm;
    for (int off = 32; off > 0; off >>= 1) {
        sqm += __shfl_down(sqm, off);
        sqc += __shfl_down(sqc, off);
    }
    if (l == 0) {
        bias[bk] = logf(1.0f / KK) - 0.5f * (sqm + sqc);
        nk[bk] = 0.f;
        if (k == 0) cnt[b] = 0;
    }
    macc[(size_t)bk * LL + l] = 0.f;
}

// Fused EM pass, occupancy-first redesign:
//  - 512 threads (8 waves); wave q owns zrows [16q,16q+16).
//  - thread (q,lg4,ln) stages row 16q+ln, cols {8lg4..+8, 32+8lg4..+8} into
//    REGISTERS: these are exactly its phase-A MFMA B-fragments -> no z LDS
//    for phase A at all (zhl eliminated, LDS 73->36 KB).
//  - phase B: wave q -> col-tile (q&3), row-chunks {2(q>>2), 2(q>>2)+1};
//    partials of the two waves sharing a col-tile merge via macc atomics.
//  - 2 barriers/tile; deep prefetch (tile t+1 global loads issued at tile top).
__global__ __launch_bounds__(512, 4) void k_empass(const float* __restrict__ z,
                                                   float* __restrict__ mean,
                                                   float* __restrict__ bias,
                                                   float* __restrict__ nk,
                                                   float* __restrict__ macc,
                                                   int* __restrict__ cnt,
                                                   const float* __restrict__ M,
                                                   const float* __restrict__ IA,
                                                   float* __restrict__ out_pi,
                                                   float* __restrict__ out_trace) {
    __shared__ __align__(16) unsigned short mhl[2][32][ZSB];   // mean hi/lo, rows 20-31 zero
    __shared__ __align__(16) unsigned short zT[64][ZTS];       // z hi, [col][row]
    __shared__ __align__(16) unsigned short ptT[32][PTTS];     // posteriors [comp][zrow]
    __shared__ __align__(16) float bias_s[32];                 // comps >=20: -1e30
    __shared__ float nkred[8][KK];
    __shared__ int isLast;
    int t = threadIdx.x;
    int lane = t & 63;
    int q = t >> 6;             // wave id 0..7, owns zrows [16q,16q+16)
    int ln = lane & 15;
    int lg4 = lane >> 4;        // 0..3
    int b = blockIdx.y;
    size_t zbase = ((size_t)b * NN + (size_t)blockIdx.x * (TILE * NT)) * LL;
    int zr = q * 16 + ln;       // this thread's z row (tile-local)
    int fbase = zr * 16 + 2 * lg4;  // float4 index of first staged segment

    // ---- stage mean (hi/lo split) + zero pad rows + bias ----
    for (int i = t; i < KK * LL; i += 512) {
        float f = mean[(size_t)b * KK * LL + i];
        int k = i >> 6, c = i & 63;
        unsigned short h = f2bf(f);
        mhl[0][k][c] = h;
        mhl[1][k][c] = f2bf(f - bf2f(h));
    }
    for (int i = 20 * ZSB + t; i < 32 * ZSB; i += 512) {
        (&mhl[0][0][0])[i] = 0;
        (&mhl[1][0][0])[i] = 0;
    }
    if (t < 32) bias_s[t] = (t < KK) ? bias[b * KK + t] : -1e30f;

    const float4* zg = (const float4*)(z + zbase);
    float4 pf[4];
    // prologue: issue tile-0 loads (latency hides under mean staging)
    pf[0] = zg[fbase];
    pf[1] = zg[fbase + 1];
    pf[2] = zg[fbase + 8];
    pf[3] = zg[fbase + 9];
    __syncthreads();
    float4 b0 = *(const float4*)&bias_s[lg4 * 4];
    float4 b1 = *(const float4*)&bias_s[16 + lg4 * 4];
    // hoist mean fragments: [ks*4 + {mh0,ml0,mh1,ml1}]
    s16x8 mf[8];
    #pragma unroll
    for (int ks = 0; ks < 2; ++ks) {
        int kc = ks * 32 + lg4 * 8;
        mf[ks * 4 + 0] = *(const s16x8*)&mhl[0][ln][kc];
        mf[ks * 4 + 1] = *(const s16x8*)&mhl[1][ln][kc];
        mf[ks * 4 + 2] = *(const s16x8*)&mhl[0][16 + ln][kc];
        mf[ks * 4 + 3] = *(const s16x8*)&mhl[1][16 + ln][kc];
    }

    int ct = q & 3;                 // phase-B col-tile
    int chb = 2 * (q >> 2);         // phase-B row-chunk base (0 or 2)
    f32x4 bacc0 = {0.f, 0.f, 0.f, 0.f};
    f32x4 bacc1 = {0.f, 0.f, 0.f, 0.f};
    float nkp0[4] = {0.f, 0.f, 0.f, 0.f};
    float nkp1[4] = {0.f, 0.f, 0.f, 0.f};

    for (int tt = 0; tt < NT; ++tt) {
        // ---- convert staged regs -> bf16 hi/lo fragments (phase-A B-operand) ----
        s16x8 zh0, zl0, zh1, zl1;
        #pragma unroll
        for (int i = 0; i < 2; ++i) {
            float4 v = pf[i];
            float vv[4] = {v.x, v.y, v.z, v.w};
            #pragma unroll
            for (int j = 0; j < 4; ++j) {
                unsigned short h = f2bf(vv[j]);
                zh0[4 * i + j] = (short)h;
                zl0[4 * i + j] = (short)f2bf(vv[j] - bf2f(h));
            }
        }
        #pragma unroll
        for (int i = 0; i < 2; ++i) {
            float4 v = pf[2 + i];
            float vv[4] = {v.x, v.y, v.z, v.w};
            #pragma unroll
            for (int j = 0; j < 4; ++j) {
                unsigned short h = f2bf(vv[j]);
                zh1[4 * i + j] = (short)h;
                zl1[4 * i + j] = (short)f2bf(vv[j] - bf2f(h));
            }
        }
        // ---- issue next tile's loads (consumed after bar2) ----
        if (tt + 1 < NT) {
            size_t o = (size_t)(tt + 1) * 2048;
            pf[0] = zg[o + fbase];
            pf[1] = zg[o + fbase + 1];
            pf[2] = zg[o + fbase + 8];
            pf[3] = zg[o + fbase + 9];
        }
        // ---- write zT for current tile (window: after bar2(t-1), before bar1) ----
        #pragma unroll
        for (int e = 0; e < 8; ++e) {
            zT[8 * lg4 + e][zr]      = (unsigned short)zh0[e];
            zT[32 + 8 * lg4 + e][zr] = (unsigned short)zh1[e];
        }

        // ---- phase A: D[comp][zrow] = mean·zᵀ (3-product bf16 split) ----
        f32x4 acc0 = (f32x4){b0.x, b0.y, b0.z, b0.w};
        f32x4 acc1 = (f32x4){b1.x, b1.y, b1.z, b1.w};
        acc0 = MFMA_BF16(mf[0], zh0, acc0, 0, 0, 0);
        acc0 = MFMA_BF16(mf[1], zh0, acc0, 0, 0, 0);
        acc0 = MFMA_BF16(mf[0], zl0, acc0, 0, 0, 0);
        acc0 = MFMA_BF16(mf[4], zh1, acc0, 0, 0, 0);
        acc0 = MFMA_BF16(mf[5], zh1, acc0, 0, 0, 0);
        acc0 = MFMA_BF16(mf[4], zl1, acc0, 0, 0, 0);
        acc1 = MFMA_BF16(mf[2], zh0, acc1, 0, 0, 0);
        acc1 = MFMA_BF16(mf[3], zh0, acc1, 0, 0, 0);
        acc1 = MFMA_BF16(mf[2], zl0, acc1, 0, 0, 0);
        acc1 = MFMA_BF16(mf[6], zh1, acc1, 0, 0, 0);
        acc1 = MFMA_BF16(mf[7], zh1, acc1, 0, 0, 0);
        acc1 = MFMA_BF16(mf[6], zl1, acc1, 0, 0, 0);

        // ---- softmax over comps (regs + 2+2 shfls), branchless ----
        {
            float m = fmaxf(fmaxf(fmaxf(acc0[0], acc0[1]), fmaxf(acc0[2], acc0[3])),
                            fmaxf(fmaxf(acc1[0], acc1[1]), fmaxf(acc1[2], acc1[3])));
            m = fmaxf(m, __shfl_xor(m, 16));
            m = fmaxf(m, __shfl_xor(m, 32));
            float e0[4], e1[4];
            float sm = 0.f;
            #pragma unroll
            for (int j = 0; j < 4; ++j) {
                e0[j] = __expf(acc0[j] - m); sm += e0[j];
                e1[j] = __expf(acc1[j] - m); sm += e1[j];
            }
            sm += __shfl_xor(sm, 16);
            sm += __shfl_xor(sm, 32);
            float inv = 1.0f / sm;
            #pragma unroll
            for (int j = 0; j < 4; ++j) {
                float p0 = e0[j] * inv;
                float p1 = e1[j] * inv;
                nkp0[j] += p0;
                nkp1[j] += p1;
                ptT[lg4 * 4 + j][zr] = f2bf(p0);
                ptT[16 + lg4 * 4 + j][zr] = f2bf(p1);
            }
        }
        __syncthreads();    // bar1: ptT + zT complete

        // ---- phase B: D[comp][col] partial; wave q -> cols ct*16..+16 ----
        #pragma unroll
        for (int chi = 0; chi < 2; ++chi) {
            int rr = (chb + chi) * 32 + lg4 * 8;
            s16x8 zb  = *(const s16x8*)&zT[ct * 16 + ln][rr];
            s16x8 af0 = *(const s16x8*)&ptT[ln][rr];
            s16x8 af1 = *(const s16x8*)&ptT[16 + ln][rr];
            bacc0 = MFMA_BF16(af0, zb, bacc0, 0, 0, 0);
            bacc1 = MFMA_BF16(af1, zb, bacc1, 0, 0, 0);
        }
        __syncthreads();    // bar2: all B-reads done; zT/ptT reusable
    }

    // ---- Nk reduce: sum over ln lanes ----
    #pragma unroll
    for (int j = 0; j < 4; ++j) {
        nkp0[j] += __shfl_xor(nkp0[j], 1);
        nkp0[j] += __shfl_xor(nkp0[j], 2);
        nkp0[j] += __shfl_xor(nkp0[j], 4);
        nkp0[j] += __shfl_xor(nkp0[j], 8);
        nkp1[j] += __shfl_xor(nkp1[j], 1);
        nkp1[j] += __shfl_xor(nkp1[j], 2);
        nkp1[j] += __shfl_xor(nkp1[j], 4);
        nkp1[j] += __shfl_xor(nkp1[j], 8);
    }
    if (ln == 0) {
        #pragma unroll
        for (int j = 0; j < 4; ++j) nkred[q][lg4 * 4 + j] = nkp0[j];
        if (lg4 == 0) {
            #pragma unroll
            for (int j = 0; j < 4; ++j) nkred[q][16 + j] = nkp1[j];
        }
    }

    // ---- macc atomics: comp = 4lg4+reg (and 16+reg), col = 16ct+ln ----
    int col = ct * 16 + ln;
    #pragma unroll
    for (int reg = 0; reg < 4; ++reg) {
        int comp = lg4 * 4 + reg;
        atomicAdd(&macc[((size_t)b * KK + comp) * LL + col], bacc0[reg]);
    }
    if (lg4 == 0) {
        #pragma unroll
        for (int reg = 0; reg < 4; ++reg)
            atomicAdd(&macc[((size_t)b * KK + 16 + reg) * LL + col], bacc1[reg]);
    }
    __syncthreads();
    if (t < KK) {
        float sum = 0.f;
        #pragma unroll
        for (int w = 0; w < 8; ++w) sum += nkred[w][t];
        atomicAdd(&nk[b * KK + t], sum);
    }
    __syncthreads();            // all this block's atomics retired
    if (t == 0) {
        __threadfence();
        int old = atomicAdd(&cnt[b], 1);
        isLast = (old == CHUNKS - 1) ? 1 : 0;
    }
    __syncthreads();
    if (!isLast) return;

    // ---- finalize batch b (last block; waves 0-3 cover 20 comps) ----
    if (q < 4) {
        float* fs = (float*)&zT[0][0];
        float* sraw = fs + q * 160;
        float* smean = sraw + 64;
        int l = lane;
        #pragma unroll
        for (int kc5 = 0; kc5 < 5; ++kc5) {
            int comp = kc5 * 4 + q;
            int bk = b * KK + comp;
            size_t mb = (size_t)bk * LL;
            float nkv = 0.f;
            if (l == 0) nkv = atomicExch(&nk[bk], 0.f);
            nkv = __shfl(nkv, 0);
            float nkc = fmaxf(nkv, 1e-22f);
            float raw = atomicExch(&macc[mb + l], 0.f) / nkc;
            sraw[l] = raw;
            float nm = 0.f;
            #pragma unroll 8
            for (int m = 0; m < 64; ++m) nm += sraw[m] * M[m * 64 + l];
            mean[mb + l] = nm;
            smean[l] = nm;
            float cm = 0.f;
            #pragma unroll 8
            for (int m = 0; m < 64; ++m) cm += smean[m] * IA[m * 64 + l];
            float sqm = nm * nm;
            float sqc = cm * cm;
            #pragma unroll
            for (int off = 32; off > 0; off >>= 1) {
                sqm += __shfl_down(sqm, off);
                sqc += __shfl_down(sqc, off);
            }
            if (l == 0) {
                float pi = nkc * (1.0f / NN);
                bias[bk] = logf(pi) - 0.5f * (sqm + sqc);
                out_pi[bk] = pi;
                out_trace[bk] = 1.0f;
            }
        }
    }
    if (t == 0) cnt[b] = 0;
}

extern "C" void kernel_launch(void* const* d_in, const int* in_sizes, int n_in,
                              void* d_out, int out_size, void* d_ws, size_t ws_size,
                              hipStream_t stream) {
    const float* z = (const float*)d_in[0];
    const float* A = (const float*)d_in[1];
    const int* idxs = (const int*)d_in[2];

    float* out_pi = (float*)d_out;
    float* out_mean = out_pi + BB * KK;
    float* out_trace = out_mean + (size_t)BB * KK * LL;

    float* ws = (float*)d_ws;
    float* IA = ws;
    float* M = ws + 4096;
    float* bias = ws + 8192;
    float* nk = ws + 9472;
    float* macc = ws + 10752;
    int* cnt = (int*)(ws + 92672);

    k_setup<<<1, 256, 0, stream>>>(A, IA, M);
    k_init<<<dim3(KK, BB), 64, 0, stream>>>(z, idxs, M, IA, out_mean, bias, nk, macc, cnt);
    for (int it = 0; it < 5; ++it) {
        k_empass<<<dim3(CHUNKS, BB), 512, 0, stream>>>(z, out_mean, bias, nk, macc,
                                                       cnt, M, IA, out_pi, out_trace);
    }
}